// Round 6
// baseline (4152.457 us; speedup 1.0000x reference)
//
#include <hip/hip_runtime.h>
#include <hip/hip_bf16.h>
#include <cstddef>
#include <cstdint>

#define NNODES 50000
#define NR 3
#define NE 800000
#define HIDF 128
#define OUTF 64
#define NEG_SLOPE 0.01f
#define SCAN_T 1024
#define NCHUNK ((NNODES + SCAN_T - 1) / SCAN_T)   // 49

typedef __attribute__((ext_vector_type(8))) short short8;
typedef __attribute__((ext_vector_type(4))) float f32x4;

__device__ __forceinline__ float bf_lo(uint v) { return __uint_as_float(v << 16); }
__device__ __forceinline__ float bf_hi(uint v) { return __uint_as_float(v & 0xffff0000u); }
__device__ __forceinline__ uint bf_rne(float f) {
    uint u = __float_as_uint(f);
    return (u + 0x7fffu + ((u >> 16) & 1u)) >> 16;
}
__device__ __forceinline__ uint bf_pack(float a, float b) {
    return bf_rne(a) | (bf_rne(b) << 16);
}

// ---------------------------------------------------------------------------
// 0a) Cast x -> packed bf16
// ---------------------------------------------------------------------------
__global__ __launch_bounds__(256) void k_cast_x(const float* __restrict__ x,
                                                uint* __restrict__ xb) {
    int i = blockIdx.x * blockDim.x + threadIdx.x;
    if (i >= NNODES * (HIDF / 2)) return;
    float2 v = *(const float2*)(x + (size_t)i * 2);
    xb[i] = bf_pack(v.x, v.y);
}

// ---------------------------------------------------------------------------
// 0b) Weight swizzle into MFMA B-frag order (hypothesis A)
// ---------------------------------------------------------------------------
#define WSW_LAYER_U 24576
__global__ __launch_bounds__(256) void k_cast_w(const float* __restrict__ W0,
                                                const float* __restrict__ Wl,
                                                uint* __restrict__ Wsw) {
    int u = blockIdx.x * blockDim.x + threadIdx.x;
    if (u >= 5 * WSW_LAYER_U) return;
    int l    = u / WSW_LAYER_U;
    int rem  = u - l * WSW_LAYER_U;
    int r    = rem >> 13;
    int rem2 = rem & 8191;
    int ks   = rem2 >> 11;
    int rem3 = rem2 & 2047;
    int ct   = rem3 >> 8;
    int rem4 = rem3 & 255;
    int lane = rem4 >> 2;
    int j2   = rem4 & 3;
    int k = ks * 32 + (lane >> 4) * 8 + 2 * j2;
    int n = ct * 16 + (lane & 15);
    const float* src = (l == 0) ? W0 : (Wl + (size_t)(l - 1) * NR * HIDF * HIDF);
    const float* p = src + ((size_t)r * HIDF + k) * HIDF + n;
    Wsw[u] = bf_pack(p[0], p[HIDF]);
}

// ---------------------------------------------------------------------------
// 1) Degrees
// ---------------------------------------------------------------------------
__global__ __launch_bounds__(256) void k_degrees(const int* __restrict__ esrc,
                                                 const int* __restrict__ edst,
                                                 int* __restrict__ deg_out,
                                                 int* __restrict__ deg_in) {
    int idx = blockIdx.x * blockDim.x + threadIdx.x;
    if (idx >= NR * NE) return;
    int r = idx / NE;
    int s = esrc[idx];
    int d = edst[idx];
    atomicAdd(&deg_out[r * NNODES + s], 1);
    atomicAdd(&deg_in[r * NNODES + d], 1);
}

// ---------------------------------------------------------------------------
// 2) Norms
// ---------------------------------------------------------------------------
__global__ __launch_bounds__(256) void k_norms(const int* __restrict__ deg_out,
                                               const int* __restrict__ deg_in,
                                               float* __restrict__ out_norm,
                                               float* __restrict__ in_norm) {
    int idx = blockIdx.x * blockDim.x + threadIdx.x;
    if (idx >= NR * NNODES) return;
    int dout = deg_out[idx];
    int din  = deg_in[idx];
    out_norm[idx] = rsqrtf((float)(dout > 1 ? dout : 1));
    in_norm[idx]  = rsqrtf((float)(din  > 1 ? din  : 1));
}

// ---------------------------------------------------------------------------
// 3) CSR build
// ---------------------------------------------------------------------------
__global__ __launch_bounds__(SCAN_T) void k_scan1(const int* __restrict__ deg_in,
                                                  int* __restrict__ row_ptr,
                                                  int* __restrict__ csums) {
    __shared__ int buf[SCAN_T];
    int r = blockIdx.x / NCHUNK;
    int c = blockIdx.x % NCHUNK;
    int tid = threadIdx.x;
    int i = c * SCAN_T + tid;
    int v = (i < NNODES) ? deg_in[r * NNODES + i] : 0;
    buf[tid] = v;
    __syncthreads();
    for (int off = 1; off < SCAN_T; off <<= 1) {
        int t = (tid >= off) ? buf[tid - off] : 0;
        __syncthreads();
        buf[tid] += t;
        __syncthreads();
    }
    if (i < NNODES) row_ptr[r * (NNODES + 1) + i + 1] = buf[tid];
    if (tid == SCAN_T - 1) csums[r * NCHUNK + c] = buf[SCAN_T - 1];
}

__global__ void k_scan2(const int* __restrict__ csums, int* __restrict__ coffs) {
    int r = threadIdx.x;
    if (r >= NR) return;
    int run = 0;
    for (int c = 0; c < NCHUNK; ++c) {
        coffs[r * NCHUNK + c] = run;
        run += csums[r * NCHUNK + c];
    }
}

__global__ __launch_bounds__(SCAN_T) void k_scan3(int* __restrict__ row_ptr,
                                                  const int* __restrict__ coffs) {
    int r = blockIdx.x / NCHUNK;
    int c = blockIdx.x % NCHUNK;
    int tid = threadIdx.x;
    int i = c * SCAN_T + tid;
    int off = coffs[r * NCHUNK + c];
    if (i < NNODES) row_ptr[r * (NNODES + 1) + i + 1] += off;
    if (tid == 0 && c == 0) row_ptr[r * (NNODES + 1)] = 0;
}

__global__ __launch_bounds__(256) void k_fill_csr(const int* __restrict__ esrc,
                                                  const int* __restrict__ edst,
                                                  const int* __restrict__ row_ptr,
                                                  const float* __restrict__ out_norm,
                                                  int* __restrict__ cursor,
                                                  int* __restrict__ csr_src,
                                                  float* __restrict__ csr_w) {
    int idx = blockIdx.x * blockDim.x + threadIdx.x;
    if (idx >= NR * NE) return;
    int r = idx / NE;
    int s = esrc[idx];
    int d = edst[idx];
    int pos = atomicAdd(&cursor[r * NNODES + d], 1);
    size_t slot = (size_t)r * NE + row_ptr[r * (NNODES + 1) + d] + pos;
    csr_src[slot] = s;
    csr_w[slot] = out_norm[r * NNODES + s];
}

// ---------------------------------------------------------------------------
// 4) Aggregation (dual write: fp32 agg + packed bf16 aggB)
// ---------------------------------------------------------------------------
__global__ __launch_bounds__(256) void k_aggregate(const uint* __restrict__ hin,
                                                   const float* __restrict__ in_norm,
                                                   const int* __restrict__ row_ptr,
                                                   const int* __restrict__ csr_src,
                                                   const float* __restrict__ csr_w,
                                                   float* __restrict__ agg,
                                                   uint* __restrict__ aggB) {
    int wave = blockIdx.x * 4 + (threadIdx.x >> 6);
    if (wave >= NR * NNODES) return;
    int r = wave / NNODES;
    int n = wave - r * NNODES;
    int lane = threadIdx.x & 63;
    int start = row_ptr[r * (NNODES + 1) + n];
    int end   = row_ptr[r * (NNODES + 1) + n + 1];
    const int*   cs = csr_src + (size_t)r * NE;
    const float* cw = csr_w  + (size_t)r * NE;
    float acc0 = 0.f, acc1 = 0.f;
    int i = start;
    for (; i + 4 <= end; i += 4) {
        int s0 = cs[i], s1 = cs[i + 1], s2 = cs[i + 2], s3 = cs[i + 3];
        float w0 = cw[i], w1 = cw[i + 1], w2 = cw[i + 2], w3 = cw[i + 3];
        uint v0 = hin[(size_t)s0 * (HIDF / 2) + lane];
        uint v1 = hin[(size_t)s1 * (HIDF / 2) + lane];
        uint v2 = hin[(size_t)s2 * (HIDF / 2) + lane];
        uint v3 = hin[(size_t)s3 * (HIDF / 2) + lane];
        acc0 = fmaf(w0, bf_lo(v0), acc0); acc1 = fmaf(w0, bf_hi(v0), acc1);
        acc0 = fmaf(w1, bf_lo(v1), acc0); acc1 = fmaf(w1, bf_hi(v1), acc1);
        acc0 = fmaf(w2, bf_lo(v2), acc0); acc1 = fmaf(w2, bf_hi(v2), acc1);
        acc0 = fmaf(w3, bf_lo(v3), acc0); acc1 = fmaf(w3, bf_hi(v3), acc1);
    }
    for (; i < end; ++i) {
        int s = cs[i];
        float w = cw[i];
        uint v = hin[(size_t)s * (HIDF / 2) + lane];
        acc0 = fmaf(w, bf_lo(v), acc0);
        acc1 = fmaf(w, bf_hi(v), acc1);
    }
    float wn = in_norm[r * NNODES + n];
    float a0 = acc0 * wn, a1 = acc1 * wn;
    *(float2*)(agg + (size_t)wave * HIDF + 2 * lane) = make_float2(a0, a1);
    aggB[(size_t)wave * (HIDF / 2) + lane] = bf_pack(a0, a1);
}

// ---------------------------------------------------------------------------
// 5) fp32 vector conv (verified output path)
// ---------------------------------------------------------------------------
__global__ __launch_bounds__(256) void k_conv_mm(const float* __restrict__ agg,
                                                 const float* __restrict__ W,
                                                 const float* __restrict__ bias,
                                                 uint* __restrict__ hout,
                                                 int act) {
    __shared__ float At[16][68];
    __shared__ float Bt[16][128];
    int tid = threadIdx.x;
    int tx = tid & 15;
    int ty = tid >> 4;
    int block_row = blockIdx.x * 64;

    int arow = tid >> 2;
    int akq  = (tid & 3) * 4;
    int grow = block_row + arow;
    int kb   = tid >> 4;
    int bcol = (tid & 15) * 8;

    float acc[4][8];
#pragma unroll
    for (int i = 0; i < 4; ++i)
#pragma unroll
        for (int j = 0; j < 8; ++j) acc[i][j] = 0.f;

    for (int c = 0; c < NR * (HIDF / 16); ++c) {
        int r  = c >> 3;
        int k0 = (c & 7) * 16;
        float4 av = make_float4(0.f, 0.f, 0.f, 0.f);
        if (grow < NNODES)
            av = *(const float4*)(agg + ((size_t)r * NNODES + grow) * HIDF + k0 + akq);
        At[akq + 0][arow] = av.x;
        At[akq + 1][arow] = av.y;
        At[akq + 2][arow] = av.z;
        At[akq + 3][arow] = av.w;
        const float* wp = W + ((size_t)r * HIDF + (k0 + kb)) * HIDF + bcol;
        float4 b0v = *(const float4*)(wp);
        float4 b1v = *(const float4*)(wp + 4);
        *(float4*)&Bt[kb][bcol]     = b0v;
        *(float4*)&Bt[kb][bcol + 4] = b1v;
        __syncthreads();
#pragma unroll
        for (int kk = 0; kk < 16; ++kk) {
            float4 a  = *(const float4*)&At[kk][ty * 4];
            float4 b0 = *(const float4*)&Bt[kk][tx * 8];
            float4 b1 = *(const float4*)&Bt[kk][tx * 8 + 4];
            float avv[4] = {a.x, a.y, a.z, a.w};
            float bvv[8] = {b0.x, b0.y, b0.z, b0.w, b1.x, b1.y, b1.z, b1.w};
#pragma unroll
            for (int i = 0; i < 4; ++i)
#pragma unroll
                for (int j = 0; j < 8; ++j)
                    acc[i][j] = fmaf(avv[i], bvv[j], acc[i][j]);
        }
        __syncthreads();
    }

    const float inv3 = 1.f / 3.f;
    float bm[8];
#pragma unroll
    for (int j = 0; j < 8; ++j) {
        int col = tx * 8 + j;
        bm[j] = (bias[col] + bias[HIDF + col] + bias[2 * HIDF + col]) * inv3;
    }
#pragma unroll
    for (int i = 0; i < 4; ++i) {
        int row = block_row + ty * 4 + i;
        if (row >= NNODES) continue;
        float v[8];
#pragma unroll
        for (int j = 0; j < 8; ++j) {
            float t = acc[i][j] * inv3 + bm[j];
            if (act) t = (t > 0.f) ? t : NEG_SLOPE * t;
            v[j] = t;
        }
        uint4 pk;
        pk.x = bf_pack(v[0], v[1]);
        pk.y = bf_pack(v[2], v[3]);
        pk.z = bf_pack(v[4], v[5]);
        pk.w = bf_pack(v[6], v[7]);
        *(uint4*)(hout + (size_t)row * (HIDF / 2) + tx * 4) = pk;
    }
}

// ---------------------------------------------------------------------------
// 5t) Round-3 MFMA conv VERBATIM (incl. epilogue) -> h_test (diagnostic)
// ---------------------------------------------------------------------------
__global__ __launch_bounds__(256) void k_conv_mfma(const uint* __restrict__ agg,
                                                   const uint* __restrict__ WswL,
                                                   const float* __restrict__ bias,
                                                   uint* __restrict__ hout,
                                                   int act) {
    __shared__ float C_lds[64][132];
    int tid = threadIdx.x;
    int w    = tid >> 6;
    int lane = tid & 63;
    int quad = lane >> 4;
    int i16  = lane & 15;
    int m0 = blockIdx.x * 64;
    int m  = m0 + w * 16 + i16;

    f32x4 acc[8];
#pragma unroll
    for (int ct = 0; ct < 8; ++ct) acc[ct] = (f32x4){0.f, 0.f, 0.f, 0.f};

    const short8* Bf = (const short8*)WswL;
#pragma unroll
    for (int r = 0; r < NR; ++r) {
        size_t arow = ((size_t)r * NNODES + m) * (HIDF / 2);
#pragma unroll
        for (int ks = 0; ks < 4; ++ks) {
            short8 a = *(const short8*)(agg + arow + ks * 16 + quad * 4);
            const short8* bp = Bf + ((size_t)((r * 4 + ks) * 8) << 6) + lane;
#pragma unroll
            for (int ct = 0; ct < 8; ++ct)
                acc[ct] = __builtin_amdgcn_mfma_f32_16x16x32_bf16(a, bp[(size_t)ct << 6], acc[ct], 0, 0, 0);
        }
    }

    const float inv3 = 1.f / 3.f;
#pragma unroll
    for (int ct = 0; ct < 8; ++ct) {
        int col = ct * 16 + i16;
        float bm = (bias[col] + bias[HIDF + col] + bias[2 * HIDF + col]) * inv3;
#pragma unroll
        for (int reg = 0; reg < 4; ++reg) {
            float v = acc[ct][reg] * inv3 + bm;
            if (act) v = (v > 0.f) ? v : NEG_SLOPE * v;
            C_lds[w * 16 + quad * 4 + reg][col] = v;
        }
    }
    __syncthreads();
    for (int t = tid; t < 64 * 16; t += 256) {
        int row = t >> 4;
        int seg = t & 15;
        if (m0 + row >= NNODES) continue;
        float4 v0 = *(const float4*)&C_lds[row][seg * 8];
        float4 v1 = *(const float4*)&C_lds[row][seg * 8 + 4];
        uint4 pk;
        pk.x = bf_pack(v0.x, v0.y);
        pk.y = bf_pack(v0.z, v0.w);
        pk.z = bf_pack(v1.x, v1.y);
        pk.w = bf_pack(v1.z, v1.w);
        *(uint4*)(hout + (size_t)(m0 + row) * (HIDF / 2) + seg * 4) = pk;
    }
}

// ---------------------------------------------------------------------------
// 6) Final linear (verified)
// ---------------------------------------------------------------------------
__global__ __launch_bounds__(256) void k_final(const uint* __restrict__ h,
                                               const float* __restrict__ Wout,
                                               const float* __restrict__ bout,
                                               float* __restrict__ out) {
    int tid = threadIdx.x;
    int col = tid & 63;
    int row = blockIdx.x * 4 + (tid >> 6);
    if (row >= NNODES) return;
    const uint* hp = h + (size_t)row * (HIDF / 2);
    float acc = bout[col];
#pragma unroll 8
    for (int ku = 0; ku < HIDF / 2; ++ku) {
        uint v = hp[ku];
        acc = fmaf(bf_lo(v), Wout[(2 * ku) * OUTF + col], acc);
        acc = fmaf(bf_hi(v), Wout[(2 * ku + 1) * OUTF + col], acc);
    }
    out[(size_t)row * OUTF + col] = acc;
}

// ===========================================================================
// DIAGNOSTICS
// ===========================================================================
__device__ __forceinline__ float Aval(int m, int k) { return (float)(((m * 7 + k * 3) % 13) - 6); }
__device__ __forceinline__ float Bval(int k, int n) { return (float)(((k * 5 + n * 11) % 17) - 8); }

// cnts[0]: d0 != rn (layout-A fail); cnts[1]: d0 != rs (0 => D-transposed world);
// cnts[2]: mfma(a_c,b_s) != rn (0 => asym B-split world)
__global__ void k_mfma_test(int* __restrict__ cnts) {
    int lane = threadIdx.x;
    if (lane >= 64) return;
    int quad = lane >> 4, i16 = lane & 15;
    short8 a_c, b_c, b_s;
#pragma unroll
    for (int j = 0; j < 8; ++j) {
        int kc  = quad * 8 + j;
        int ksp = (j >> 2) * 16 + quad * 4 + (j & 3);
        a_c[j] = (short)bf_rne(Aval(i16, kc));
        b_c[j] = (short)bf_rne(Bval(kc, i16));
        b_s[j] = (short)bf_rne(Bval(ksp, i16));
    }
    f32x4 z = (f32x4){0.f, 0.f, 0.f, 0.f};
    f32x4 d0 = __builtin_amdgcn_mfma_f32_16x16x32_bf16(a_c, b_c, z, 0, 0, 0);
    f32x4 d3 = __builtin_amdgcn_mfma_f32_16x16x32_bf16(a_c, b_s, z, 0, 0, 0);
    int b0 = 0, b1 = 0, b2 = 0;
    for (int reg = 0; reg < 4; ++reg) {
        int qr = quad * 4 + reg;
        float rn = 0.f, rs = 0.f;
        for (int k = 0; k < 32; ++k) {
            rn += Aval(qr, k) * Bval(k, i16);
            rs += Aval(i16, k) * Bval(k, qr);
        }
        if (d0[reg] != rn) ++b0;
        if (d0[reg] != rs) ++b1;
        if (d3[reg] != rn) ++b2;
    }
    if (b0) atomicAdd(&cnts[0], b0);
    if (b1) atomicAdd(&cnts[1], b1);
    if (b2) atomicAdd(&cnts[2], b2);
}

// cnts[3]: bit-exact inverse-mapping check of Wsw vs original W
__global__ __launch_bounds__(256) void k_castw_check(const float* __restrict__ W0,
                                                     const float* __restrict__ Wl,
                                                     const uint* __restrict__ Wsw,
                                                     int* __restrict__ cnts) {
    int i = blockIdx.x * 256 + threadIdx.x;   // (l,r,k,n): 5*3*128*128
    bool bad = false;
    if (i < 5 * 3 * 128 * 128) {
        int l = i / 49152;
        int rem = i - l * 49152;
        int r = rem / 16384;
        int rem2 = rem - r * 16384;
        int k = rem2 >> 7, n = rem2 & 127;
        const float* src = (l == 0) ? W0 : (Wl + (size_t)(l - 1) * NR * HIDF * HIDF);
        uint expv = bf_rne(src[((size_t)r * HIDF + k) * HIDF + n]);
        int ks = k >> 5, kin = k & 31, quad = kin >> 3, j = kin & 7;
        int lane = quad * 16 + (n & 15), ct = n >> 4, j2 = j >> 1;
        uint u = (uint)l * WSW_LAYER_U + r * 8192 + ks * 2048 + ct * 256 + lane * 4 + j2;
        uint v = Wsw[u];
        uint half = (j & 1) ? (v >> 16) : (v & 0xffffu);
        bad = (half != expv);
    }
    unsigned long long mm = __ballot(bad);
    if ((threadIdx.x & 63) == 0 && mm) atomicAdd(&cnts[3], __popcll(mm));
}

// cnts[4]: compare h_test (r3 conv) vs h (verified conv_mm), rel 5% + abs 5e-3
__global__ __launch_bounds__(256) void k_cmp(const uint* __restrict__ h_test,
                                             const uint* __restrict__ h,
                                             int* __restrict__ cnts) {
    int i = blockIdx.x * 256 + threadIdx.x;   // uint index, N*64
    bool b1 = false, b2 = false;
    if (i < NNODES * (HIDF / 2)) {
        uint a = h_test[i], b = h[i];
        float alo = bf_lo(a), ahi = bf_hi(a);
        float blo = bf_lo(b), bhi = bf_hi(b);
        b1 = fabsf(alo - blo) > 0.05f * fabsf(blo) + 5e-3f;
        b2 = fabsf(ahi - bhi) > 0.05f * fabsf(bhi) + 5e-3f;
    }
    unsigned long long m1 = __ballot(b1);
    unsigned long long m2 = __ballot(b2);
    if ((threadIdx.x & 63) == 0 && (m1 | m2))
        atomicAdd(&cnts[4], __popcll(m1) + __popcll(m2));
}

// Result kernel: guaranteed top-1 by duration; WRITE_SIZE = (1+code)*1024 KiB
__global__ __launch_bounds__(256) void k_res(const int* __restrict__ cnts,
                                             float4* __restrict__ target) {
    int code = 0;
    if (cnts[0] != 0) code |= 1;        // layout-A synthetic test FAILED
    if (cnts[1] == 0) code |= 2;        // D-transposed world matched
    if (cnts[2] == 0) code |= 4;        // asym B-split world matched
    if (cnts[3] != 0) code |= 8;        // cast_w mapping bad
    if (cnts[4] > 6400)   code |= 16;   // r3 conv vs verified h: >0.1% bad
    if (cnts[4] > 640000) code |= 32;   // >10% bad (structural)
    float v = 1.f + threadIdx.x * 1e-7f;
    for (int i = 0; i < 1000000; ++i) v = fmaf(v, 1.0000001f, 1e-9f);
    int total = (1 + code) * 65536;     // float4 count = (1+code) MiB
    float4 val = make_float4(v, v, v, v);
    for (int i = blockIdx.x * 256 + threadIdx.x; i < total; i += 65536) target[i] = val;
}

// ---------------------------------------------------------------------------
// Host launcher
// ---------------------------------------------------------------------------
extern "C" void kernel_launch(void* const* d_in, const int* in_sizes, int n_in,
                              void* d_out, int out_size, void* d_ws, size_t ws_size,
                              hipStream_t stream) {
    const float* x    = (const float*)d_in[0];
    const int*   esrc = (const int*)d_in[1];
    const int*   edst = (const int*)d_in[2];
    const float* W0   = (const float*)d_in[3];
    const float* b0   = (const float*)d_in[4];
    const float* Wl   = (const float*)d_in[5];
    const float* bl   = (const float*)d_in[6];
    const float* Wout = (const float*)d_in[7];
    const float* bout = (const float*)d_in[8];
    float* out = (float*)d_out;

    char* ws = (char*)d_ws;
    size_t off = 0;
    auto carve = [&](size_t bytes) {
        size_t p = off;
        off += (bytes + 255) & ~(size_t)255;
        return p;
    };
    const size_t SZ_RN_I = (size_t)NR * NNODES * 4;
    size_t o_deg_out = carve(SZ_RN_I);
    size_t o_deg_in  = carve(SZ_RN_I);
    size_t o_cursor  = carve(SZ_RN_I);
    size_t o_cnts    = carve(256);
    size_t zero_span = off;
    size_t o_out_nrm = carve(SZ_RN_I);
    size_t o_in_nrm  = carve(SZ_RN_I);
    size_t o_row_ptr = carve((size_t)NR * (NNODES + 1) * 4);
    size_t o_csums   = carve((size_t)NR * NCHUNK * 4);
    size_t o_coffs   = carve((size_t)NR * NCHUNK * 4);
    size_t o_csr     = carve((size_t)NR * NE * 4);
    size_t o_csrw    = carve((size_t)NR * NE * 4);
    size_t o_agg     = carve((size_t)NR * NNODES * HIDF * 4);        // fp32 (also k_res target)
    size_t o_aggB    = carve((size_t)NR * NNODES * (HIDF / 2) * 4);
    size_t o_xb      = carve((size_t)NNODES * (HIDF / 2) * 4);
    size_t o_h       = carve((size_t)NNODES * (HIDF / 2) * 4);
    size_t o_htest   = carve((size_t)NNODES * (HIDF / 2) * 4);
    size_t o_wsw     = carve((size_t)5 * WSW_LAYER_U * 4);
    (void)ws_size;

    int*   deg_out  = (int*)(ws + o_deg_out);
    int*   deg_in   = (int*)(ws + o_deg_in);
    int*   cursor   = (int*)(ws + o_cursor);
    int*   cnts     = (int*)(ws + o_cnts);
    float* out_norm = (float*)(ws + o_out_nrm);
    float* in_norm  = (float*)(ws + o_in_nrm);
    int*   row_ptr  = (int*)(ws + o_row_ptr);
    int*   csums    = (int*)(ws + o_csums);
    int*   coffs    = (int*)(ws + o_coffs);
    int*   csr_src  = (int*)(ws + o_csr);
    float* csr_w    = (float*)(ws + o_csrw);
    float* agg      = (float*)(ws + o_agg);
    uint*  aggB     = (uint*)(ws + o_aggB);
    uint*  xb       = (uint*)(ws + o_xb);
    uint*  h        = (uint*)(ws + o_h);
    uint*  h_test   = (uint*)(ws + o_htest);
    uint*  Wsw      = (uint*)(ws + o_wsw);

    hipMemsetAsync(ws, 0, zero_span, stream);

    int nEdgeBlocks = (NR * NE + 255) / 256;
    k_cast_x<<<(NNODES * (HIDF / 2) + 255) / 256, 256, 0, stream>>>(x, xb);
    k_cast_w<<<(5 * WSW_LAYER_U + 255) / 256, 256, 0, stream>>>(W0, Wl, Wsw);
    k_degrees<<<nEdgeBlocks, 256, 0, stream>>>(esrc, edst, deg_out, deg_in);
    k_norms<<<(NR * NNODES + 255) / 256, 256, 0, stream>>>(deg_out, deg_in, out_norm, in_norm);
    k_scan1<<<NR * NCHUNK, SCAN_T, 0, stream>>>(deg_in, row_ptr, csums);
    k_scan2<<<1, 64, 0, stream>>>(csums, coffs);
    k_scan3<<<NR * NCHUNK, SCAN_T, 0, stream>>>(row_ptr, coffs);
    k_fill_csr<<<nEdgeBlocks, 256, 0, stream>>>(esrc, edst, row_ptr, out_norm, cursor, csr_src, csr_w);

    const int aggBlocks  = (NR * NNODES + 3) / 4;
    const int mmBlocks   = (NNODES + 63) / 64;

    const uint* hin = xb;
    for (int l = 0; l < 5; ++l) {
        k_aggregate<<<aggBlocks, 256, 0, stream>>>(hin, in_norm, row_ptr, csr_src, csr_w, agg, aggB);
        const float* Wp = (l == 0) ? W0 : Wl + (size_t)(l - 1) * NR * HIDF * HIDF;
        const float* bp = (l == 0) ? b0 : bl + (size_t)(l - 1) * NR * HIDF;
        k_conv_mm<<<mmBlocks, 256, 0, stream>>>(agg, Wp, bp, h, (l < 4) ? 1 : 0);
        if (l == 0) {
            k_mfma_test<<<1, 64, 0, stream>>>(cnts);
            k_castw_check<<<(5 * 3 * 128 * 128 + 255) / 256, 256, 0, stream>>>(W0, Wl, Wsw, cnts);
            k_conv_mfma<<<mmBlocks, 256, 0, stream>>>(aggB, Wsw, b0, h_test, 1);
            k_cmp<<<(NNODES * (HIDF / 2) + 255) / 256, 256, 0, stream>>>(h_test, h, cnts);
        }
        hin = h;
    }
    k_final<<<(NNODES + 3) / 4, 256, 0, stream>>>(h, Wout, bout, out);
    k_res<<<256, 256, 0, stream>>>(cnts, (float4*)(ws + o_agg));
}